// Round 7
// baseline (1570.160 us; speedup 1.0000x reference)
//
#include <hip/hip_runtime.h>
#include <hip/hip_bf16.h>
#include <math.h>

#define BB 32
#define QQ 900
#define NMM 300
#define DD 256
#define CCC 90
#define NCC 91
#define KB 5
#define MK 5

__device__ __forceinline__ float wsumf(float v){
#pragma unroll
  for(int o=32;o>0;o>>=1) v += __shfl_xor(v,o,64);
  return v;
}
__device__ __forceinline__ int wsumi(int v){
#pragma unroll
  for(int o=32;o>0;o>>=1) v += __shfl_xor(v,o,64);
  return v;
}
__device__ __forceinline__ void wargmax(float& v,int& i){
#pragma unroll
  for(int o=32;o>0;o>>=1){
    float v2=__shfl_xor(v,o,64); int i2=__shfl_xor(i,o,64);
    if(v2>v || (v2==v && i2<i)){v=v2;i=i2;}
  }
}

// zero ism+acc, write f32 canary {1,1} to out (overwritten by asgs_fin if pipeline runs)
__global__ void asgs_zero(int* ism, float* acc, float* out){
  int i=blockIdx.x*blockDim.x+threadIdx.x;
  if(i<BB*QQ) ism[i]=0;
  if(i<64) acc[i]=0.f;
  if(i<2) out[i]=1.0f;
}

__global__ void asgs_prep_matched(const float* __restrict__ obj,const int* __restrict__ src,
    float* __restrict__ matched,float* __restrict__ invf,float* __restrict__ invs,int* __restrict__ ism){
  int wid=(blockIdx.x*blockDim.x+threadIdx.x)>>6, lane=threadIdx.x&63;
  if(wid>=BB*NMM) return;
  int b=wid/NMM, n=wid-b*NMM;
  int q=src[b*NMM+n];
  float4 v=*(const float4*)(obj+((size_t)(b*QQ+q))*DD+lane*4);
  *(float4*)(matched+(size_t)wid*DD+lane*4)=v;
  float ss=wsumf(v.x*v.x+v.y*v.y+v.z*v.z+v.w*v.w);
  if(lane==0){
    float nr=sqrtf(ss);
    invf[wid]=1.f/fmaxf(nr,1e-12f);
    invs[wid]=1.f/fmaxf(nr,1e-6f);
    ism[b*QQ+q]=1;
  }
}

__global__ void asgs_prep_obj(const float* __restrict__ obj,float* __restrict__ oinv){
  int wid=(blockIdx.x*blockDim.x+threadIdx.x)>>6, lane=threadIdx.x&63;
  if(wid>=BB*QQ) return;
  float4 v=*(const float4*)(obj+(size_t)wid*DD+lane*4);
  float ss=wsumf(v.x*v.x+v.y*v.y+v.z*v.z+v.w*v.w);
  if(lane==0) oinv[wid]=1.f/fmaxf(sqrtf(ss),1e-12f);
}

__global__ void asgs_prep_protos(const float* __restrict__ pr,float* __restrict__ pscale){
  int wid=(blockIdx.x*blockDim.x+threadIdx.x)>>6, lane=threadIdx.x&63;
  if(wid>=CCC) return;
  float4 v=*(const float4*)(pr+(size_t)wid*DD+lane*4);
  float ss=wsumf(v.x*v.x+v.y*v.y+v.z*v.z+v.w*v.w);
  if(lane==0) pscale[wid]=1.f/fmaxf(sqrtf(ss),1e-6f);
}

// one dot per (matched-row, class) serves sims (fnorm) and S (safe_norm*pscale/tau) + S^T
__global__ void asgs_simsS(const float* __restrict__ matched,const float* __restrict__ pr,
    const float* __restrict__ invf,const float* __restrict__ invs,const float* __restrict__ pscale,
    float* __restrict__ sims,float* __restrict__ S,float* __restrict__ ST){
  int wid=(blockIdx.x*blockDim.x+threadIdx.x)>>6, lane=threadIdx.x&63;
  if(wid>=BB*NMM) return;
  float4 m=*(const float4*)(matched+(size_t)wid*DD+lane*4);
  float fi=invf[wid], si=invs[wid];
  for(int c=0;c<CCC;c++){
    float4 p=*(const float4*)(pr+(size_t)c*DD+lane*4);
    float d=wsumf(m.x*p.x+m.y*p.y+m.z*p.z+m.w*p.w);
    if(lane==0){
      sims[(size_t)wid*CCC+c]=d*fi;
      float s=d*si*pscale[c]*10.0f;   // /TAU, TAU=0.1
      S[(size_t)wid*CCC+c]=s;
      ST[(size_t)c*(BB*NMM)+wid]=s;
    }
  }
}

// per (b,c): member count + top-K_B by dist desc (tie -> lower n)
__global__ void asgs_ctopk(const float* __restrict__ sims,const int* __restrict__ lab,
    int* __restrict__ cnt,int* __restrict__ topi){
  int wid=(blockIdx.x*blockDim.x+threadIdx.x)>>6, lane=threadIdx.x&63;
  if(wid>=BB*CCC) return;
  int b=wid/CCC, c=wid-b*CCC;
  float lv[KB]; int li[KB];
#pragma unroll
  for(int j=0;j<KB;j++){lv[j]=-3.4e38f;li[j]=1<<30;}
  int mc=0;
  for(int n=lane;n<NMM;n+=64){
    bool mem = lab[b*NMM+n]==c;
    float dd = mem ? (1.0f - sims[(size_t)(b*NMM+n)*CCC+c]) : -1.0e9f;
    if(mem) mc++;
    float cv=dd; int ci=n;
#pragma unroll
    for(int j=0;j<KB;j++){
      if(cv>lv[j] || (cv==lv[j] && ci<li[j])){
        float t1=lv[j]; int t2=li[j]; lv[j]=cv; li[j]=ci; cv=t1; ci=t2;
      }
    }
  }
  mc=wsumi(mc);
  for(int k=0;k<KB;k++){
    float v=lv[0]; int i=li[0];
#pragma unroll
    for(int j=1;j<KB;j++) if(lv[j]>v || (lv[j]==v && li[j]<i)){v=lv[j];i=li[j];}
    wargmax(v,i);
#pragma unroll
    for(int j=0;j<KB;j++) if(li[j]==i && lv[j]==v){lv[j]=-3.4e38f;li[j]=1<<30;}
    if(lane==0) topi[wid*KB+k]=(i<NMM)? i : 0;
  }
  if(lane==0) cnt[wid]=mc;
}

// per (b,c) block, 5 waves (one per boundary k). obj staged in LDS tiles of 64 q,
// float4-XOR-swizzled [r][c4^(r&7)]. Per-lane top-5 over its q column, wave-merged.
__global__ __launch_bounds__(320) void asgs_simq(const float* __restrict__ obj,
    const float* __restrict__ matched,const float* __restrict__ invf,
    const float* __restrict__ oinv,const int* __restrict__ ism,
    const int* __restrict__ cnt,const int* __restrict__ topi,
    float* __restrict__ tops,int* __restrict__ topq){
  __shared__ float4 tile4[64][64];
  __shared__ float bn5[KB][DD];
  int bc=blockIdx.x, b=bc/CCC;
  int cc=cnt[bc];
  int t=threadIdx.x, wave=t>>6, lane=t&63;
  for(int it=0;it<4;++it){
    int idx=it*320+t;
    int k=idx>>8, d=idx&255;
    int nidx=topi[bc*KB+k];
    float sc=(k<cc)? invf[b*NMM+nidx] : 0.0f;
    bn5[k][d]=matched[((size_t)(b*NMM+nidx))*DD+d]*sc;
  }
  float tv[MK]; int tq[MK];
#pragma unroll
  for(int m=0;m<MK;m++){tv[m]=-3.4e38f;tq[m]=1<<30;}
  const int k=wave;                    // wave w owns boundary k=w
  const float* objb=obj+(size_t)b*QQ*DD;
  const int sw=lane&7;
  for(int qt=0;qt<15;++qt){
    int q0=qt*64;
    __syncthreads();                   // bn5 ready / prev-tile reads done
    for(int it=0;it<13;++it){
      int idx=it*320+t;
      if(idx<4096){
        int r=idx>>6, c4=idx&63;
        int qr=q0+r;
        float4 v;
        if(qr<QQ) v=*(const float4*)(objb+(size_t)qr*DD+c4*4);
        else { v.x=0.f;v.y=0.f;v.z=0.f;v.w=0.f; }
        tile4[r][c4^(r&7)]=v;
      }
    }
    __syncthreads();
    int q=q0+lane;
    bool valid=q<QQ;
    float a=0.f;
#pragma unroll 4
    for(int L=0;L<64;++L){             // logical float4 column
      float4 ov=tile4[lane][L^sw];
      float4 bv=*(const float4*)(&bn5[k][L*4]);
      a+=ov.x*bv.x+ov.y*bv.y+ov.z*bv.z+ov.w*bv.w;
    }
    int qi=valid?q:0;
    float s=a*oinv[b*QQ+qi];
    bool msk=(ism[b*QQ+qi]!=0);
    float sv = valid ? (msk? -1.0e9f : s) : -3.4e38f;
    int   sq = valid ? q : (1<<30);
    float cv=sv; int ci=sq;
#pragma unroll
    for(int m=0;m<MK;m++){
      if(cv>tv[m] || (cv==tv[m] && ci<tq[m])){
        float t1=tv[m]; int t2=tq[m]; tv[m]=cv; tq[m]=ci; cv=t1; ci=t2;
      }
    }
  }
  // wave merge: 5 rounds of argmax-and-remove
  for(int m=0;m<MK;m++){
    float v=tv[0]; int i=tq[0];
#pragma unroll
    for(int j=1;j<MK;j++) if(tv[j]>v || (tv[j]==v && tq[j]<i)){v=tv[j];i=tq[j];}
    wargmax(v,i);
#pragma unroll
    for(int j=0;j<MK;j++) if(tq[j]==i && tv[j]==v){tv[j]=-3.4e38f;tq[j]=1<<30;}
    if(lane==0){
      tops[((size_t)bc*KB+k)*MK+m]=v;
      topq[((size_t)bc*KB+k)*MK+m]=i;
    }
  }
}

// per valid (b,c,k): g_bar, logits, focal loss, accumulate
__global__ __launch_bounds__(64) void asgs_focal(const float* __restrict__ obj,
    const float* __restrict__ matched,const float* __restrict__ W,const float* __restrict__ bcls,
    const int* __restrict__ cnt,const int* __restrict__ topi,
    const float* __restrict__ tops,const int* __restrict__ topq,float* __restrict__ acc){
  int bck=blockIdx.x;
  int bc=bck/KB, k=bck-bc*KB;
  if(k>=cnt[bc]) return;
  int b=bc/CCC;
  int lane=threadIdx.x;
  int idx=topi[bck];
  float4 g=*(const float4*)(matched+((size_t)(b*NMM+idx))*DD+lane*4);
  float wsum=0.f; bool any=false;
#pragma unroll
  for(int m=0;m<MK;m++){
    float s=tops[(size_t)bck*MK+m];
    if(s>0.0f){                         // DELTA = 0, strict
      any=true; wsum+=1.0f;
      int q=topq[(size_t)bck*MK+m];
      float4 u=*(const float4*)(obj+((size_t)(b*QQ+q))*DD+lane*4);
      g.x+=u.x; g.y+=u.y; g.z+=u.z; g.w+=u.w;
    }
  }
  if(!any) return;
  float inv=1.0f/(1.0f+wsum);
  g.x*=inv; g.y*=inv; g.z*=inv; g.w*=inv;
  float fls=0.f;
  for(int j=0;j<NCC;j++){
    float4 w4=*(const float4*)(W+(size_t)j*DD+lane*4);
    float x=wsumf(g.x*w4.x+g.y*w4.y+g.z*w4.z+g.w*w4.w)+bcls[j];
    float sp=log1pf(expf(-fabsf(x)));
    float sig=1.0f/(1.0f+expf(-x));
    float fl;
    if(j==NCC-1){                       // t = 1
      float ce=fmaxf(-x,0.0f)+sp;
      float om=1.0f-sig;
      fl=0.25f*ce*om*om;
    }else{                              // t = 0
      float ce=fmaxf(x,0.0f)+sp;
      fl=0.75f*ce*sig*sig;
    }
    fls+=fl;
  }
  if(lane==0){
    atomicAdd(&acc[0],fls*(1.0f/NCC));
    atomicAdd(&acc[1],1.0f);
  }
}

// per class c: lse over P column (diag masked) and S column (lab==c masked), logaddexp
__global__ __launch_bounds__(256) void asgs_lse(const float* __restrict__ pr,
    const float* __restrict__ pscale,const float* __restrict__ ST,
    const int* __restrict__ lab,float* __restrict__ lneg){
  int c=blockIdx.x, tid=threadIdx.x;
  __shared__ float pc[DD];
  __shared__ float pcol[CCC];
  __shared__ float red[256];
  pc[tid]=pr[(size_t)c*DD+tid];
  __syncthreads();
  if(tid<CCC){
    float d=0;
    for(int dd=0;dd<DD;dd++) d+=pr[(size_t)tid*DD+dd]*pc[dd];
    pcol[tid]=(tid==c)? -1.0e9f : d*pscale[tid]*pscale[c]*10.0f;
  }
  float mx=-3.4e38f;
  for(int i=tid;i<BB*NMM;i+=256){
    if(lab[i]!=c) mx=fmaxf(mx,ST[(size_t)c*(BB*NMM)+i]);
  }
  red[tid]=mx; __syncthreads();
  for(int s=128;s>0;s>>=1){ if(tid<s) red[tid]=fmaxf(red[tid],red[tid+s]); __syncthreads(); }
  float gmax=red[0]; __syncthreads();
  float sm=0;
  for(int i=tid;i<BB*NMM;i+=256){
    if(lab[i]!=c) sm+=expf(ST[(size_t)c*(BB*NMM)+i]-gmax);
  }
  red[tid]=sm; __syncthreads();
  for(int s=128;s>0;s>>=1){ if(tid<s) red[tid]+=red[tid+s]; __syncthreads(); }
  if(tid==0){
    float lseS=gmax+logf(red[0]);
    float pmx=-3.4e38f;
    for(int t2=0;t2<CCC;t2++) pmx=fmaxf(pmx,pcol[t2]);
    float ps=0;
    for(int t2=0;t2<CCC;t2++) ps+=expf(pcol[t2]-pmx);
    float lseP=pmx+logf(ps);
    float a=fmaxf(lseP,lseS);
    lneg[c]=a+log1pf(expf(-fabsf(lseP-lseS)));
  }
}

__global__ __launch_bounds__(256) void asgs_cec(const float* __restrict__ S,
    const int* __restrict__ lab,const float* __restrict__ lneg,float* __restrict__ acc){
  __shared__ float red[256];
  int tid=threadIdx.x;
  int i=blockIdx.x*256+tid;
  float v=0.f;
  if(i<BB*NMM){
    int l=lab[i];
    float pos=S[(size_t)i*CCC+l];
    float ln=lneg[l];
    float a=fmaxf(pos,ln);
    v=-pos + a + log1pf(expf(-fabsf(pos-ln)));
  }
  red[tid]=v; __syncthreads();
  for(int s=128;s>0;s>>=1){ if(tid<s) red[tid]+=red[tid+s]; __syncthreads(); }
  if(tid==0) atomicAdd(&acc[2],red[0]);
}

// f32 output — reference returns float32
__global__ void asgs_fin(const float* __restrict__ acc,float* __restrict__ out){
  if(threadIdx.x==0 && blockIdx.x==0){
    float sul=acc[0]/fmaxf(acc[1],1.0f);
    float cec=acc[2]/(float)(BB*NMM);
    out[0]=sul;
    out[1]=cec;
  }
}

extern "C" void kernel_launch(void* const* d_in,const int* in_sizes,int n_in,
                              void* d_out,int out_size,void* d_ws,size_t ws_size,
                              hipStream_t stream){
  (void)in_sizes;(void)n_in;(void)out_size;(void)ws_size;
  const float* obj=(const float*)d_in[0];
  const float* pr =(const float*)d_in[1];
  const float* W  =(const float*)d_in[2];
  const float* bcl=(const float*)d_in[3];
  const int* src  =(const int*)d_in[4];
  const int* lab  =(const int*)d_in[5];
  float* out=(float*)d_out;

  char* p=(char*)d_ws;
  auto take=[&](size_t n){ void* r=(void*)p; p+=(n+255)&~(size_t)255; return r; };
  float* matched=(float*)take((size_t)BB*NMM*DD*4);     // 9.83 MB
  float* sims  =(float*)take((size_t)BB*NMM*CCC*4);     // 3.46 MB
  float* S     =(float*)take((size_t)BB*NMM*CCC*4);     // 3.46 MB
  float* ST    =(float*)take((size_t)BB*NMM*CCC*4);     // 3.46 MB
  float* invf  =(float*)take((size_t)BB*NMM*4);
  float* invs  =(float*)take((size_t)BB*NMM*4);
  float* oinv  =(float*)take((size_t)BB*QQ*4);
  int*   ism   =(int*)  take((size_t)BB*QQ*4);
  float* pscale=(float*)take(128*4);
  int*   cnt   =(int*)  take((size_t)BB*CCC*4);
  int*   topi  =(int*)  take((size_t)BB*CCC*KB*4);
  float* tops  =(float*)take((size_t)BB*CCC*KB*MK*4);
  int*   topq  =(int*)  take((size_t)BB*CCC*KB*MK*4);
  float* lneg  =(float*)take(128*4);
  float* acc   =(float*)take(64*4);

  asgs_zero<<<(BB*QQ+255)/256,256,0,stream>>>(ism,acc,out);
  asgs_prep_matched<<<BB*NMM/4,256,0,stream>>>(obj,src,matched,invf,invs,ism);
  asgs_prep_obj<<<BB*QQ/4,256,0,stream>>>(obj,oinv);
  asgs_prep_protos<<<(CCC+3)/4,256,0,stream>>>(pr,pscale);
  asgs_simsS<<<BB*NMM/4,256,0,stream>>>(matched,pr,invf,invs,pscale,sims,S,ST);
  asgs_ctopk<<<BB*CCC/4,256,0,stream>>>(sims,lab,cnt,topi);
  asgs_simq<<<BB*CCC,320,0,stream>>>(obj,matched,invf,oinv,ism,cnt,topi,tops,topq);
  asgs_focal<<<BB*CCC*KB,64,0,stream>>>(obj,matched,W,bcl,cnt,topi,tops,topq,acc);
  asgs_lse<<<CCC,256,0,stream>>>(pr,pscale,ST,lab,lneg);
  asgs_cec<<<(BB*NMM+255)/256,256,0,stream>>>(S,lab,lneg,acc);
  asgs_fin<<<1,64,0,stream>>>(acc,out);
}

// Round 8
// 955.095 us; speedup vs baseline: 1.6440x; 1.6440x over previous
//
#include <hip/hip_runtime.h>
#include <hip/hip_bf16.h>
#include <math.h>

#define BB 32
#define QQ 900
#define NMM 300
#define DD 256
#define CCC 90
#define NCC 91
#define KB 5
#define MK 5

__device__ __forceinline__ float wsumf(float v){
#pragma unroll
  for(int o=32;o>0;o>>=1) v += __shfl_xor(v,o,64);
  return v;
}
__device__ __forceinline__ int wsumi(int v){
#pragma unroll
  for(int o=32;o>0;o>>=1) v += __shfl_xor(v,o,64);
  return v;
}
__device__ __forceinline__ void wargmax(float& v,int& i){
#pragma unroll
  for(int o=32;o>0;o>>=1){
    float v2=__shfl_xor(v,o,64); int i2=__shfl_xor(i,o,64);
    if(v2>v || (v2==v && i2<i)){v=v2;i=i2;}
  }
}

// zero ism+acc, write f32 canary {1,1} to out (overwritten by asgs_fin if pipeline runs)
__global__ void asgs_zero(int* ism, float* acc, float* out){
  int i=blockIdx.x*blockDim.x+threadIdx.x;
  if(i<BB*QQ) ism[i]=0;
  if(i<64) acc[i]=0.f;
  if(i<2) out[i]=1.0f;
}

__global__ void asgs_prep_matched(const float* __restrict__ obj,const int* __restrict__ src,
    float* __restrict__ matched,float* __restrict__ invf,float* __restrict__ invs,int* __restrict__ ism){
  int wid=(blockIdx.x*blockDim.x+threadIdx.x)>>6, lane=threadIdx.x&63;
  if(wid>=BB*NMM) return;
  int b=wid/NMM, n=wid-b*NMM;
  int q=src[b*NMM+n];
  float4 v=*(const float4*)(obj+((size_t)(b*QQ+q))*DD+lane*4);
  *(float4*)(matched+(size_t)wid*DD+lane*4)=v;
  float ss=wsumf(v.x*v.x+v.y*v.y+v.z*v.z+v.w*v.w);
  if(lane==0){
    float nr=sqrtf(ss);
    invf[wid]=1.f/fmaxf(nr,1e-12f);
    invs[wid]=1.f/fmaxf(nr,1e-6f);
    ism[b*QQ+q]=1;
  }
}

__global__ void asgs_prep_obj(const float* __restrict__ obj,float* __restrict__ oinv){
  int wid=(blockIdx.x*blockDim.x+threadIdx.x)>>6, lane=threadIdx.x&63;
  if(wid>=BB*QQ) return;
  float4 v=*(const float4*)(obj+(size_t)wid*DD+lane*4);
  float ss=wsumf(v.x*v.x+v.y*v.y+v.z*v.z+v.w*v.w);
  if(lane==0) oinv[wid]=1.f/fmaxf(sqrtf(ss),1e-12f);
}

__global__ void asgs_prep_protos(const float* __restrict__ pr,float* __restrict__ pscale){
  int wid=(blockIdx.x*blockDim.x+threadIdx.x)>>6, lane=threadIdx.x&63;
  if(wid>=CCC) return;
  float4 v=*(const float4*)(pr+(size_t)wid*DD+lane*4);
  float ss=wsumf(v.x*v.x+v.y*v.y+v.z*v.z+v.w*v.w);
  if(lane==0) pscale[wid]=1.f/fmaxf(sqrtf(ss),1e-6f);
}

// one dot per (matched-row, class) serves sims (fnorm) and S (safe_norm*pscale/tau) + S^T
__global__ void asgs_simsS(const float* __restrict__ matched,const float* __restrict__ pr,
    const float* __restrict__ invf,const float* __restrict__ invs,const float* __restrict__ pscale,
    float* __restrict__ sims,float* __restrict__ S,float* __restrict__ ST){
  int wid=(blockIdx.x*blockDim.x+threadIdx.x)>>6, lane=threadIdx.x&63;
  if(wid>=BB*NMM) return;
  float4 m=*(const float4*)(matched+(size_t)wid*DD+lane*4);
  float fi=invf[wid], si=invs[wid];
  for(int c=0;c<CCC;c++){
    float4 p=*(const float4*)(pr+(size_t)c*DD+lane*4);
    float d=wsumf(m.x*p.x+m.y*p.y+m.z*p.z+m.w*p.w);
    if(lane==0){
      sims[(size_t)wid*CCC+c]=d*fi;
      float s=d*si*pscale[c]*10.0f;   // /TAU, TAU=0.1
      S[(size_t)wid*CCC+c]=s;
      ST[(size_t)c*(BB*NMM)+wid]=s;
    }
  }
}

// per (b,c): member count + top-K_B by dist desc (tie -> lower n)
__global__ void asgs_ctopk(const float* __restrict__ sims,const int* __restrict__ lab,
    int* __restrict__ cnt,int* __restrict__ topi){
  int wid=(blockIdx.x*blockDim.x+threadIdx.x)>>6, lane=threadIdx.x&63;
  if(wid>=BB*CCC) return;
  int b=wid/CCC, c=wid-b*CCC;
  float lv[KB]; int li[KB];
#pragma unroll
  for(int j=0;j<KB;j++){lv[j]=-3.4e38f;li[j]=1<<30;}
  int mc=0;
  for(int n=lane;n<NMM;n+=64){
    bool mem = lab[b*NMM+n]==c;
    float dd = mem ? (1.0f - sims[(size_t)(b*NMM+n)*CCC+c]) : -1.0e9f;
    if(mem) mc++;
    float cv=dd; int ci=n;
#pragma unroll
    for(int j=0;j<KB;j++){
      if(cv>lv[j] || (cv==lv[j] && ci<li[j])){
        float t1=lv[j]; int t2=li[j]; lv[j]=cv; li[j]=ci; cv=t1; ci=t2;
      }
    }
  }
  mc=wsumi(mc);
  for(int k=0;k<KB;k++){
    float v=lv[0]; int i=li[0];
#pragma unroll
    for(int j=1;j<KB;j++) if(lv[j]>v || (lv[j]==v && li[j]<i)){v=lv[j];i=li[j];}
    wargmax(v,i);
#pragma unroll
    for(int j=0;j<KB;j++) if(li[j]==i && lv[j]==v){lv[j]=-3.4e38f;li[j]=1<<30;}
    if(lane==0) topi[wid*KB+k]=(i<NMM)? i : 0;
  }
  if(lane==0) cnt[wid]=mc;
}

// v3: one wave per (b,c). All 5 boundaries in LDS (broadcast reads); obj rows read
// directly from global/L2 (L1 catches 64B-line reuse across consecutive d4).
// 2 q per lane per pass (8 passes x 128 q). Per-lane top-5 per k in registers,
// single-wave wargmax merge. No tile staging, no __syncthreads in main loop.
__global__ __launch_bounds__(64) void asgs_simq(const float* __restrict__ obj,
    const float* __restrict__ matched,const float* __restrict__ invf,
    const float* __restrict__ oinv,const int* __restrict__ ism,
    const int* __restrict__ cnt,const int* __restrict__ topi,
    float* __restrict__ tops,int* __restrict__ topq){
  __shared__ float bn5[KB][DD];
  int bc=blockIdx.x, b=bc/CCC;
  int cc=cnt[bc];
  int lane=threadIdx.x;
  // stage the 5 scaled boundary rows: 320 float4 / 64 lanes = 5 iters
#pragma unroll
  for(int it=0;it<5;++it){
    int idx=it*64+lane;              // float4 index in [0,320)
    int k=idx>>6, c4=idx&63;
    int nidx=topi[bc*KB+k];
    float sc=(k<cc)? invf[b*NMM+nidx] : 0.0f;
    float4 v=*(const float4*)(matched+((size_t)(b*NMM+nidx))*DD+c4*4);
    v.x*=sc; v.y*=sc; v.z*=sc; v.w*=sc;
    *(float4*)(&bn5[k][c4*4])=v;
  }
  __syncthreads();

  float tv[KB][MK]; int tq[KB][MK];
#pragma unroll
  for(int k=0;k<KB;k++){
#pragma unroll
    for(int m=0;m<MK;m++){tv[k][m]=-3.4e38f;tq[k][m]=1<<30;}
  }
  const float* objb=obj+(size_t)b*QQ*DD;
  for(int p=0;p<8;++p){
    int qa=p*128+lane, qb=qa+64;
    bool va=qa<QQ, vb=qb<QQ;
    int ra=va?qa:0, rb=vb?qb:0;
    const float* pa=objb+(size_t)ra*DD;
    const float* pb=objb+(size_t)rb*DD;
    float aA[KB], aB[KB];
#pragma unroll
    for(int k=0;k<KB;k++){aA[k]=0.f;aB[k]=0.f;}
#pragma unroll 2
    for(int d4=0;d4<64;++d4){
      float4 oa=*(const float4*)(pa+d4*4);
      float4 ob=*(const float4*)(pb+d4*4);
#pragma unroll
      for(int k=0;k<KB;k++){
        float4 bv=*(const float4*)(&bn5[k][d4*4]);
        aA[k]+=oa.x*bv.x+oa.y*bv.y+oa.z*bv.z+oa.w*bv.w;
        aB[k]+=ob.x*bv.x+ob.y*bv.y+ob.z*bv.z+ob.w*bv.w;
      }
    }
    float oiA=oinv[b*QQ+ra], oiB=oinv[b*QQ+rb];
    bool mA=(ism[b*QQ+ra]!=0), mB=(ism[b*QQ+rb]!=0);
#pragma unroll
    for(int k=0;k<KB;k++){
      float sA = va ? (mA? -1.0e9f : aA[k]*oiA) : -3.4e38f;
      int   iA = va ? qa : (1<<30);
      float cv=sA; int ci=iA;
#pragma unroll
      for(int m=0;m<MK;m++){
        if(cv>tv[k][m] || (cv==tv[k][m] && ci<tq[k][m])){
          float t1=tv[k][m]; int t2=tq[k][m]; tv[k][m]=cv; tq[k][m]=ci; cv=t1; ci=t2;
        }
      }
      float sB = vb ? (mB? -1.0e9f : aB[k]*oiB) : -3.4e38f;
      int   iB = vb ? qb : (1<<30);
      cv=sB; ci=iB;
#pragma unroll
      for(int m=0;m<MK;m++){
        if(cv>tv[k][m] || (cv==tv[k][m] && ci<tq[k][m])){
          float t1=tv[k][m]; int t2=tq[k][m]; tv[k][m]=cv; tq[k][m]=ci; cv=t1; ci=t2;
        }
      }
    }
  }
  // single-wave merge per k: 5 rounds of argmax-and-remove
#pragma unroll
  for(int k=0;k<KB;k++){
    for(int m=0;m<MK;m++){
      float v=tv[k][0]; int i=tq[k][0];
#pragma unroll
      for(int j=1;j<MK;j++) if(tv[k][j]>v || (tv[k][j]==v && tq[k][j]<i)){v=tv[k][j];i=tq[k][j];}
      wargmax(v,i);
#pragma unroll
      for(int j=0;j<MK;j++) if(tq[k][j]==i && tv[k][j]==v){tv[k][j]=-3.4e38f;tq[k][j]=1<<30;}
      if(lane==0){
        tops[((size_t)bc*KB+k)*MK+m]=v;
        topq[((size_t)bc*KB+k)*MK+m]=i;
      }
    }
  }
}

// per valid (b,c,k): g_bar, logits, focal loss, accumulate
__global__ __launch_bounds__(64) void asgs_focal(const float* __restrict__ obj,
    const float* __restrict__ matched,const float* __restrict__ W,const float* __restrict__ bcls,
    const int* __restrict__ cnt,const int* __restrict__ topi,
    const float* __restrict__ tops,const int* __restrict__ topq,float* __restrict__ acc){
  int bck=blockIdx.x;
  int bc=bck/KB, k=bck-bc*KB;
  if(k>=cnt[bc]) return;
  int b=bc/CCC;
  int lane=threadIdx.x;
  int idx=topi[bck];
  float4 g=*(const float4*)(matched+((size_t)(b*NMM+idx))*DD+lane*4);
  float wsum=0.f; bool any=false;
#pragma unroll
  for(int m=0;m<MK;m++){
    float s=tops[(size_t)bck*MK+m];
    if(s>0.0f){                         // DELTA = 0, strict
      any=true; wsum+=1.0f;
      int q=topq[(size_t)bck*MK+m];
      float4 u=*(const float4*)(obj+((size_t)(b*QQ+q))*DD+lane*4);
      g.x+=u.x; g.y+=u.y; g.z+=u.z; g.w+=u.w;
    }
  }
  if(!any) return;
  float inv=1.0f/(1.0f+wsum);
  g.x*=inv; g.y*=inv; g.z*=inv; g.w*=inv;
  float fls=0.f;
  for(int j=0;j<NCC;j++){
    float4 w4=*(const float4*)(W+(size_t)j*DD+lane*4);
    float x=wsumf(g.x*w4.x+g.y*w4.y+g.z*w4.z+g.w*w4.w)+bcls[j];
    float sp=log1pf(expf(-fabsf(x)));
    float sig=1.0f/(1.0f+expf(-x));
    float fl;
    if(j==NCC-1){                       // t = 1
      float ce=fmaxf(-x,0.0f)+sp;
      float om=1.0f-sig;
      fl=0.25f*ce*om*om;
    }else{                              // t = 0
      float ce=fmaxf(x,0.0f)+sp;
      fl=0.75f*ce*sig*sig;
    }
    fls+=fl;
  }
  if(lane==0){
    atomicAdd(&acc[0],fls*(1.0f/NCC));
    atomicAdd(&acc[1],1.0f);
  }
}

// per class c: lse over P column (diag masked) and S column (lab==c masked), logaddexp
__global__ __launch_bounds__(256) void asgs_lse(const float* __restrict__ pr,
    const float* __restrict__ pscale,const float* __restrict__ ST,
    const int* __restrict__ lab,float* __restrict__ lneg){
  int c=blockIdx.x, tid=threadIdx.x;
  __shared__ float pc[DD];
  __shared__ float pcol[CCC];
  __shared__ float red[256];
  pc[tid]=pr[(size_t)c*DD+tid];
  __syncthreads();
  if(tid<CCC){
    float d=0;
    for(int dd=0;dd<DD;dd++) d+=pr[(size_t)tid*DD+dd]*pc[dd];
    pcol[tid]=(tid==c)? -1.0e9f : d*pscale[tid]*pscale[c]*10.0f;
  }
  float mx=-3.4e38f;
  for(int i=tid;i<BB*NMM;i+=256){
    if(lab[i]!=c) mx=fmaxf(mx,ST[(size_t)c*(BB*NMM)+i]);
  }
  red[tid]=mx; __syncthreads();
  for(int s=128;s>0;s>>=1){ if(tid<s) red[tid]=fmaxf(red[tid],red[tid+s]); __syncthreads(); }
  float gmax=red[0]; __syncthreads();
  float sm=0;
  for(int i=tid;i<BB*NMM;i+=256){
    if(lab[i]!=c) sm+=expf(ST[(size_t)c*(BB*NMM)+i]-gmax);
  }
  red[tid]=sm; __syncthreads();
  for(int s=128;s>0;s>>=1){ if(tid<s) red[tid]+=red[tid+s]; __syncthreads(); }
  if(tid==0){
    float lseS=gmax+logf(red[0]);
    float pmx=-3.4e38f;
    for(int t2=0;t2<CCC;t2++) pmx=fmaxf(pmx,pcol[t2]);
    float ps=0;
    for(int t2=0;t2<CCC;t2++) ps+=expf(pcol[t2]-pmx);
    float lseP=pmx+logf(ps);
    float a=fmaxf(lseP,lseS);
    lneg[c]=a+log1pf(expf(-fabsf(lseP-lseS)));
  }
}

__global__ __launch_bounds__(256) void asgs_cec(const float* __restrict__ S,
    const int* __restrict__ lab,const float* __restrict__ lneg,float* __restrict__ acc){
  __shared__ float red[256];
  int tid=threadIdx.x;
  int i=blockIdx.x*256+tid;
  float v=0.f;
  if(i<BB*NMM){
    int l=lab[i];
    float pos=S[(size_t)i*CCC+l];
    float ln=lneg[l];
    float a=fmaxf(pos,ln);
    v=-pos + a + log1pf(expf(-fabsf(pos-ln)));
  }
  red[tid]=v; __syncthreads();
  for(int s=128;s>0;s>>=1){ if(tid<s) red[tid]+=red[tid+s]; __syncthreads(); }
  if(tid==0) atomicAdd(&acc[2],red[0]);
}

// f32 output — reference returns float32
__global__ void asgs_fin(const float* __restrict__ acc,float* __restrict__ out){
  if(threadIdx.x==0 && blockIdx.x==0){
    float sul=acc[0]/fmaxf(acc[1],1.0f);
    float cec=acc[2]/(float)(BB*NMM);
    out[0]=sul;
    out[1]=cec;
  }
}

extern "C" void kernel_launch(void* const* d_in,const int* in_sizes,int n_in,
                              void* d_out,int out_size,void* d_ws,size_t ws_size,
                              hipStream_t stream){
  (void)in_sizes;(void)n_in;(void)out_size;(void)ws_size;
  const float* obj=(const float*)d_in[0];
  const float* pr =(const float*)d_in[1];
  const float* W  =(const float*)d_in[2];
  const float* bcl=(const float*)d_in[3];
  const int* src  =(const int*)d_in[4];
  const int* lab  =(const int*)d_in[5];
  float* out=(float*)d_out;

  char* p=(char*)d_ws;
  auto take=[&](size_t n){ void* r=(void*)p; p+=(n+255)&~(size_t)255; return r; };
  float* matched=(float*)take((size_t)BB*NMM*DD*4);     // 9.83 MB
  float* sims  =(float*)take((size_t)BB*NMM*CCC*4);     // 3.46 MB
  float* S     =(float*)take((size_t)BB*NMM*CCC*4);     // 3.46 MB
  float* ST    =(float*)take((size_t)BB*NMM*CCC*4);     // 3.46 MB
  float* invf  =(float*)take((size_t)BB*NMM*4);
  float* invs  =(float*)take((size_t)BB*NMM*4);
  float* oinv  =(float*)take((size_t)BB*QQ*4);
  int*   ism   =(int*)  take((size_t)BB*QQ*4);
  float* pscale=(float*)take(128*4);
  int*   cnt   =(int*)  take((size_t)BB*CCC*4);
  int*   topi  =(int*)  take((size_t)BB*CCC*KB*4);
  float* tops  =(float*)take((size_t)BB*CCC*KB*MK*4);
  int*   topq  =(int*)  take((size_t)BB*CCC*KB*MK*4);
  float* lneg  =(float*)take(128*4);
  float* acc   =(float*)take(64*4);

  asgs_zero<<<(BB*QQ+255)/256,256,0,stream>>>(ism,acc,out);
  asgs_prep_matched<<<BB*NMM/4,256,0,stream>>>(obj,src,matched,invf,invs,ism);
  asgs_prep_obj<<<BB*QQ/4,256,0,stream>>>(obj,oinv);
  asgs_prep_protos<<<(CCC+3)/4,256,0,stream>>>(pr,pscale);
  asgs_simsS<<<BB*NMM/4,256,0,stream>>>(matched,pr,invf,invs,pscale,sims,S,ST);
  asgs_ctopk<<<BB*CCC/4,256,0,stream>>>(sims,lab,cnt,topi);
  asgs_simq<<<BB*CCC,64,0,stream>>>(obj,matched,invf,oinv,ism,cnt,topi,tops,topq);
  asgs_focal<<<BB*CCC*KB,64,0,stream>>>(obj,matched,W,bcl,cnt,topi,tops,topq,acc);
  asgs_lse<<<CCC,256,0,stream>>>(pr,pscale,ST,lab,lneg);
  asgs_cec<<<(BB*NMM+255)/256,256,0,stream>>>(S,lab,lneg,acc);
  asgs_fin<<<1,64,0,stream>>>(acc,out);
}